// Round 7
// baseline (320.560 us; speedup 1.0000x reference)
//
#include <hip/hip_runtime.h>
#include <hip/hip_bf16.h>

#define B_ 8
#define N_ 1024
#define DIN 256
#define DOUT 256
#define R_ 4

typedef __attribute__((ext_vector_type(8))) short bf16x8;
typedef __attribute__((ext_vector_type(4))) float f32x4;
typedef __attribute__((ext_vector_type(4))) int i32x4;

__device__ __forceinline__ unsigned short f2bf(float f) {
    union { float f; unsigned int u; } v; v.f = f;
    unsigned int u = v.u;
    u += 0x7fffu + ((u >> 16) & 1u);
    return (unsigned short)(u >> 16);
}
__device__ __forceinline__ float bf2f(unsigned short h) {
    union { float f; unsigned int u; } v; v.u = ((unsigned int)h) << 16;
    return v.f;
}

// async global->LDS, 16B/lane. LDS dest = wave-uniform base + lane*16.
__device__ __forceinline__ void gl_lds16(const void* g, void* l) {
    __builtin_amdgcn_global_load_lds(
        (const __attribute__((address_space(1))) unsigned int*)g,
        (__attribute__((address_space(3))) unsigned int*)l, 16, 0, 0);
}

// ---- k0: swizzle rel_w (f32 [R][D][K]) into bf16 MFMA B-fragment layout ----
__global__ __launch_bounds__(256) void k0_swz(const float* __restrict__ rw,
                                              unsigned short* __restrict__ swzW) {
    int t = blockIdx.x * 256 + threadIdx.x;  // 0..32767
    int lane = t & 63, nb = (t >> 6) & 15, ks = (t >> 10) & 7, r = t >> 13;
    int m = lane & 15, q = lane >> 4;
    const float* src = rw + ((r * DOUT + nb * 16 + m) * DIN) + ks * 32 + q * 8;
    float4 v0 = *(const float4*)src;
    float4 v1 = *(const float4*)(src + 4);
    bf16x8 o;
    o[0] = (short)f2bf(v0.x); o[1] = (short)f2bf(v0.y);
    o[2] = (short)f2bf(v0.z); o[3] = (short)f2bf(v0.w);
    o[4] = (short)f2bf(v1.x); o[5] = (short)f2bf(v1.y);
    o[6] = (short)f2bf(v1.z); o[7] = (short)f2bf(v1.w);
    *(bf16x8*)(swzW + (long)t * 8) = o;
}

// ---- k1: G[j][d] = e[j]*(node@rel_w^T + rel_b)[j][d], B-fragment layout -----
__global__ __launch_bounds__(256) void k1_proj(const float* __restrict__ node,
        const unsigned short* __restrict__ swzW, const float* __restrict__ rel_b,
        const float* __restrict__ attn_w,
        unsigned short* __restrict__ fswz, unsigned short* __restrict__ ebf) {
    __shared__ unsigned short Wbuf[2][8192];
    int bid = blockIdx.x;
    int nt = bid & 15, r = (bid >> 4) & 3, b = bid >> 6;
    int w = threadIdx.x >> 6, lane = threadIdx.x & 63;
    int m = lane & 15, q = lane >> 4;
    int n0 = nt * 64 + w * 16;

    const float* Abase = node + ((b * N_ + n0 + m) * DIN) + q * 8;
    const unsigned short* Wsrc = swzW + r * 65536;

#pragma unroll
    for (int i = 0; i < 4; i++)
        gl_lds16(Wsrc + (w * 4 + i) * 512 + lane * 8, &Wbuf[0][(w * 4 + i) * 512]);

    f32x4 acc[16];
#pragma unroll
    for (int i = 0; i < 16; i++) acc[i] = (f32x4)0.0f;

    float4 a0 = *(const float4*)(Abase);
    float4 a1 = *(const float4*)(Abase + 4);

    for (int ks = 0; ks < 8; ks++) {
        int cur = ks & 1;
        __syncthreads();
        if (ks < 7) {
#pragma unroll
            for (int i = 0; i < 4; i++)
                gl_lds16(Wsrc + ((ks + 1) * 16 + w * 4 + i) * 512 + lane * 8,
                         &Wbuf[cur ^ 1][(w * 4 + i) * 512]);
        }
        bf16x8 af;
        af[0] = (short)f2bf(a0.x); af[1] = (short)f2bf(a0.y);
        af[2] = (short)f2bf(a0.z); af[3] = (short)f2bf(a0.w);
        af[4] = (short)f2bf(a1.x); af[5] = (short)f2bf(a1.y);
        af[6] = (short)f2bf(a1.z); af[7] = (short)f2bf(a1.w);
        if (ks < 7) {
            a0 = *(const float4*)(Abase + (ks + 1) * 32);
            a1 = *(const float4*)(Abase + (ks + 1) * 32 + 4);
        }
#pragma unroll
        for (int nb = 0; nb < 16; nb++) {
            bf16x8 wf = *(const bf16x8*)(&Wbuf[cur][nb * 512 + lane * 8]);
            acc[nb] = __builtin_amdgcn_mfma_f32_16x16x32_bf16(af, wf, acc[nb], 0, 0, 0);
        }
    }

    float sj0 = 0.f, sj1 = 0.f, sj2 = 0.f, sj3 = 0.f;
    float bias[16], aw[16];
#pragma unroll
    for (int nb = 0; nb < 16; nb++) {
        int d = nb * 16 + m;
        bias[nb] = rel_b[r * DOUT + d];
        aw[nb] = attn_w[DOUT + d];
        sj0 += (acc[nb][0] + bias[nb]) * aw[nb];
        sj1 += (acc[nb][1] + bias[nb]) * aw[nb];
        sj2 += (acc[nb][2] + bias[nb]) * aw[nb];
        sj3 += (acc[nb][3] + bias[nb]) * aw[nb];
    }
#pragma unroll
    for (int mk = 1; mk <= 8; mk <<= 1) {
        sj0 += __shfl_xor(sj0, mk, 64);
        sj1 += __shfl_xor(sj1, mk, 64);
        sj2 += __shfl_xor(sj2, mk, 64);
        sj3 += __shfl_xor(sj3, mk, 64);
    }
    float e0 = __expf(sj0), e1 = __expf(sj1), e2 = __expf(sj2), e3 = __expf(sj3);

    int slice = b * R_ + r;
    int js = n0 >> 5;
    int jhi = (n0 >> 4) & 1;
    int qp = jhi * 2 + (q >> 1);
    int jj0 = (q & 1) * 4;
    unsigned short* fb = fswz + ((long)(slice * 32 + js) * 16) * 512
                       + qp * 128 + m * 8 + jj0;
#pragma unroll
    for (int nb = 0; nb < 16; nb++) {
        ushort4 o;
        o.x = f2bf((acc[nb][0] + bias[nb]) * e0);
        o.y = f2bf((acc[nb][1] + bias[nb]) * e1);
        o.z = f2bf((acc[nb][2] + bias[nb]) * e2);
        o.w = f2bf((acc[nb][3] + bias[nb]) * e3);
        *(ushort4*)(fb + nb * 512) = o;
    }
    if (m == 0) {
        ushort4 o;
        o.x = f2bf(e0); o.y = f2bf(e1); o.z = f2bf(e2); o.w = f2bf(e3);
        *(ushort4*)(ebf + slice * N_ + n0 + q * 4) = o;
    }
}

// ---- k2: bit-pack adj (134MB int32 -> 4.2MB bits), fully coalesced ----------
// pk (as uint32): word[row][k], k=j>>5, bit j&31. Ballot order matches.
__global__ __launch_bounds__(256) void k2_pack(const int* __restrict__ adj,
                                               unsigned long long* __restrict__ pk) {
    int w = threadIdx.x >> 6, lane = threadIdx.x & 63;
    long rowbase = (long)blockIdx.x * 32 + w * 8;  // grid 1024, 32 rows/block
#pragma unroll 1
    for (int rr = 0; rr < 8; rr++) {
        long row = rowbase + rr;
        const int* src = adj + row * N_ + lane;
        unsigned long long* dst = pk + row * 16;
#pragma unroll
        for (int kk = 0; kk < 16; kk++) {
            int a = src[kk * 64];
            unsigned long long bm = __ballot(a != 0);
            if (lane == 0) dst[kk] = bm;
        }
    }
}

// ---- k3: accU = A @ G over a j-half + partial l ----------------------------
// adj as REGISTER-HELD bitmask (16 VGPRs/lane, loaded once) -> zero in-loop
// global loads except G staging (16KB/step LDS dbuf, global_load_lds).
// grid 1024 = slice(32, XCD-affine) x it(16) x jh(2); 33.8KB LDS -> 4 blk/CU.
__global__ __launch_bounds__(256, 4) void k3_attn(const unsigned int* __restrict__ pk,
        const unsigned short* __restrict__ fswz, const unsigned short* __restrict__ ebf,
        unsigned short* __restrict__ aggU, float* __restrict__ lbuf) {
    __shared__ unsigned short Gbuf[2][8192];  // 2 x 16KB
    __shared__ unsigned short Ebuf[512];      // 1KB: this j-half's e

    int bid = blockIdx.x;
    int slice = (bid & 7) * 4 + ((bid >> 3) & 3);  // XCD-affine slice grouping
    int rest = bid >> 5;
    int it = rest & 15, jh = rest >> 4;
    int t = threadIdx.x, lane = t & 63, w = t >> 6;
    int m = lane & 15, q = lane >> 4;
    int i0b = it * 64;

    const unsigned short* fsl = fswz + ((size_t)(slice * 32 + jh * 16)) * 8192;
    const unsigned short* esl = ebf + slice * N_ + jh * 512;

    // row bits for this lane's MFMA A-row: 512 bits = 16 uint32
    const unsigned int* pb = pk + ((size_t)slice * N_ + i0b + w * 16 + m) * 32 + jh * 16;
    unsigned int Wv[16];
    *(i32x4*)(&Wv[0])  = *(const i32x4*)(pb);
    *(i32x4*)(&Wv[4])  = *(const i32x4*)(pb + 4);
    *(i32x4*)(&Wv[8])  = *(const i32x4*)(pb + 8);
    *(i32x4*)(&Wv[12]) = *(const i32x4*)(pb + 12);
    int q8 = q * 8;

    // prologue: stage G step 0 + e-table
#pragma unroll
    for (int i = 0; i < 4; i++)
        gl_lds16(fsl + (w * 4 + i) * 512 + lane * 8, &Gbuf[0][(w * 4 + i) * 512]);
    if (w == 0)
        gl_lds16(esl + lane * 8, &Ebuf[0]);

    f32x4 acc[16];
#pragma unroll
    for (int i = 0; i < 16; i++) acc[i] = (f32x4)0.0f;
    float l = 0.f;

#pragma unroll
    for (int s = 0; s < 16; s++) {
        int cur = s & 1;
        __syncthreads();  // drains staging for step s
        if (s < 15) {
#pragma unroll
            for (int i = 0; i < 4; i++)
                gl_lds16(fsl + (size_t)(s + 1) * 8192 + (w * 4 + i) * 512 + lane * 8,
                         &Gbuf[cur ^ 1][(w * 4 + i) * 512]);
        }
        unsigned int byte = (Wv[s] >> q8) & 0xffu;  // 8 j-bits for this lane
        bf16x8 ev = *(const bf16x8*)(&Ebuf[s * 32 + q * 8]);
        const int* ei = (const int*)&ev;
        bf16x8 af;
        int* afi = (int*)&af;
#pragma unroll
        for (int p = 0; p < 4; p++) {
            unsigned int msk = (((byte >> (2 * p)) & 1u) ? 0xffffu : 0u)
                             | (((byte >> (2 * p + 1)) & 1u) ? 0xffff0000u : 0u);
            afi[p] = (int)(msk & 0x3F803F80u);  // A entries: bf16 1.0 / 0.0
            int me = ei[p] & (int)msk;          // masked e (bf16 pair) for l
            union { int i; float f; } lo, hi;
            lo.i = me << 16;
            hi.i = me & (int)0xffff0000u;
            l += lo.f + hi.f;
        }
        const unsigned short* Gb = &Gbuf[cur][lane * 8];
#pragma unroll
        for (int nb = 0; nb < 16; nb++) {
            bf16x8 bfq = *(const bf16x8*)(Gb + nb * 512);
            acc[nb] = __builtin_amdgcn_mfma_f32_16x16x32_bf16(af, bfq, acc[nb], 0, 0, 0);
        }
    }

    // partial l per row m: reduce over q
    l += __shfl_xor(l, 16, 64);
    l += __shfl_xor(l, 32, 64);
    int half = slice * 2 + jh;
    if (lane < 16)
        lbuf[half * N_ + i0b + w * 16 + lane] = l;

    // unnormalized accU (bf16): row = i0b + w*16 + q*4 + reg, col = nb*16 + m
    unsigned short* ob = aggU + ((size_t)half * N_ + i0b + w * 16 + q * 4) * DOUT + m;
#pragma unroll
    for (int nb = 0; nb < 16; nb++) {
#pragma unroll
        for (int reg = 0; reg < 4; reg++)
            ob[(size_t)reg * DOUT + nb * 16] = f2bf(acc[nb][reg]);
    }
}

// ---- k4: combine halves, gate, write out ------------------------------------
__global__ __launch_bounds__(256) void k4_out(const unsigned short* __restrict__ aggU,
        const float* __restrict__ lbuf, const float* __restrict__ gate_w,
        const float* __restrict__ gate_b, float* __restrict__ out) {
    __shared__ float red[4];
    int bid = blockIdx.x;  // 8192 = b*1024 + n
    int n = bid & 1023, b = bid >> 10;
    int d = threadIdx.x;
    float s = 0.f;
#pragma unroll
    for (int r = 0; r < R_; r++) {
        int sl = b * R_ + r;
        float a0 = bf2f(aggU[((size_t)(sl * 2 + 0) * N_ + n) * DOUT + d]);
        float a1 = bf2f(aggU[((size_t)(sl * 2 + 1) * N_ + n) * DOUT + d]);
        float lt = lbuf[(sl * 2 + 0) * N_ + n] + lbuf[(sl * 2 + 1) * N_ + n];
        float inv = (lt > 0.f) ? 1.0f / lt : 0.f;
        s += (a0 + a1) * inv;
    }
    float v = s * gate_w[d];
#pragma unroll
    for (int off = 32; off; off >>= 1) v += __shfl_down(v, off, 64);
    int lane = d & 63, wave = d >> 6;
    if (lane == 0) red[wave] = v;
    __syncthreads();
    float tot = red[0] + red[1] + red[2] + red[3];
    float g = 1.f / (1.f + __expf(-(tot + gate_b[0])));
    out[((long)(b * N_ + n)) * DOUT + d] = g * s;
}

extern "C" void kernel_launch(void* const* d_in, const int* in_sizes, int n_in,
                              void* d_out, int out_size, void* d_ws, size_t ws_size,
                              hipStream_t stream) {
    const float* node   = (const float*)d_in[0];
    const int*   adj    = (const int*)d_in[1];
    const float* rel_w  = (const float*)d_in[2];
    const float* rel_b  = (const float*)d_in[3];
    const float* attn_w = (const float*)d_in[4];
    // d_in[5] = attn_b: cancels in softmax, unused
    const float* gate_w = (const float*)d_in[6];
    const float* gate_b = (const float*)d_in[7];
    float* out = (float*)d_out;

    char* ws = (char*)d_ws;
    unsigned short* swzW = (unsigned short*)ws;                        // 524,288 B
    unsigned short* fswz = (unsigned short*)(ws + 524288);             // 16,777,216 B (G)
    unsigned short* ebf  = (unsigned short*)(ws + 17301504);           // 65,536 B
    unsigned short* aggU = (unsigned short*)(ws + 17367040);           // 33,554,432 B (bf16)
    float*          lbuf = (float*)(ws + 50921472);                    // 262,144 B
    unsigned long long* pk = (unsigned long long*)(ws + 51183616);     // 4,194,304 B

    k0_swz<<<128, 256, 0, stream>>>(rel_w, swzW);
    k2_pack<<<1024, 256, 0, stream>>>(adj, pk);
    k1_proj<<<512, 256, 0, stream>>>(node, swzW, rel_b, attn_w, fswz, ebf);
    k3_attn<<<1024, 256, 0, stream>>>((const unsigned int*)pk, fswz, ebf, aggU, lbuf);
    k4_out<<<8192, 256, 0, stream>>>(aggU, lbuf, gate_w, gate_b, out);
}

// Round 8
// 276.950 us; speedup vs baseline: 1.1575x; 1.1575x over previous
//
#include <hip/hip_runtime.h>
#include <hip/hip_bf16.h>

#define B_ 8
#define N_ 1024
#define DIN 256
#define DOUT 256
#define R_ 4

typedef __attribute__((ext_vector_type(8))) short bf16x8;
typedef __attribute__((ext_vector_type(4))) float f32x4;
typedef __attribute__((ext_vector_type(4))) int i32x4;

__device__ __forceinline__ unsigned short f2bf(float f) {
    union { float f; unsigned int u; } v; v.f = f;
    unsigned int u = v.u;
    u += 0x7fffu + ((u >> 16) & 1u);
    return (unsigned short)(u >> 16);
}
__device__ __forceinline__ float bf2f(unsigned short h) {
    union { float f; unsigned int u; } v; v.u = ((unsigned int)h) << 16;
    return v.f;
}

// async global->LDS, 16B/lane. LDS dest = wave-uniform base + lane*16.
__device__ __forceinline__ void gl_lds16(const void* g, void* l) {
    __builtin_amdgcn_global_load_lds(
        (const __attribute__((address_space(1))) unsigned int*)g,
        (__attribute__((address_space(3))) unsigned int*)l, 16, 0, 0);
}

// ---- k0: swizzle rel_w (f32 [R][D][K]) into bf16 MFMA B-fragment layout ----
__global__ __launch_bounds__(256) void k0_swz(const float* __restrict__ rw,
                                              unsigned short* __restrict__ swzW) {
    int t = blockIdx.x * 256 + threadIdx.x;  // 0..32767
    int lane = t & 63, nb = (t >> 6) & 15, ks = (t >> 10) & 7, r = t >> 13;
    int m = lane & 15, q = lane >> 4;
    const float* src = rw + ((r * DOUT + nb * 16 + m) * DIN) + ks * 32 + q * 8;
    float4 v0 = *(const float4*)src;
    float4 v1 = *(const float4*)(src + 4);
    bf16x8 o;
    o[0] = (short)f2bf(v0.x); o[1] = (short)f2bf(v0.y);
    o[2] = (short)f2bf(v0.z); o[3] = (short)f2bf(v0.w);
    o[4] = (short)f2bf(v1.x); o[5] = (short)f2bf(v1.y);
    o[6] = (short)f2bf(v1.z); o[7] = (short)f2bf(v1.w);
    *(bf16x8*)(swzW + (long)t * 8) = o;
}

// ---- k1: G[j][d] = e[j]*(node@rel_w^T + rel_b)[j][d], B-fragment layout -----
__global__ __launch_bounds__(256) void k1_proj(const float* __restrict__ node,
        const unsigned short* __restrict__ swzW, const float* __restrict__ rel_b,
        const float* __restrict__ attn_w,
        unsigned short* __restrict__ fswz, unsigned short* __restrict__ ebf) {
    __shared__ unsigned short Wbuf[2][8192];
    int bid = blockIdx.x;
    int nt = bid & 15, r = (bid >> 4) & 3, b = bid >> 6;
    int w = threadIdx.x >> 6, lane = threadIdx.x & 63;
    int m = lane & 15, q = lane >> 4;
    int n0 = nt * 64 + w * 16;

    const float* Abase = node + ((b * N_ + n0 + m) * DIN) + q * 8;
    const unsigned short* Wsrc = swzW + r * 65536;

#pragma unroll
    for (int i = 0; i < 4; i++)
        gl_lds16(Wsrc + (w * 4 + i) * 512 + lane * 8, &Wbuf[0][(w * 4 + i) * 512]);

    f32x4 acc[16];
#pragma unroll
    for (int i = 0; i < 16; i++) acc[i] = (f32x4)0.0f;

    float4 a0 = *(const float4*)(Abase);
    float4 a1 = *(const float4*)(Abase + 4);

    for (int ks = 0; ks < 8; ks++) {
        int cur = ks & 1;
        __syncthreads();
        if (ks < 7) {
#pragma unroll
            for (int i = 0; i < 4; i++)
                gl_lds16(Wsrc + ((ks + 1) * 16 + w * 4 + i) * 512 + lane * 8,
                         &Wbuf[cur ^ 1][(w * 4 + i) * 512]);
        }
        bf16x8 af;
        af[0] = (short)f2bf(a0.x); af[1] = (short)f2bf(a0.y);
        af[2] = (short)f2bf(a0.z); af[3] = (short)f2bf(a0.w);
        af[4] = (short)f2bf(a1.x); af[5] = (short)f2bf(a1.y);
        af[6] = (short)f2bf(a1.z); af[7] = (short)f2bf(a1.w);
        if (ks < 7) {
            a0 = *(const float4*)(Abase + (ks + 1) * 32);
            a1 = *(const float4*)(Abase + (ks + 1) * 32 + 4);
        }
#pragma unroll
        for (int nb = 0; nb < 16; nb++) {
            bf16x8 wf = *(const bf16x8*)(&Wbuf[cur][nb * 512 + lane * 8]);
            acc[nb] = __builtin_amdgcn_mfma_f32_16x16x32_bf16(af, wf, acc[nb], 0, 0, 0);
        }
    }

    float sj0 = 0.f, sj1 = 0.f, sj2 = 0.f, sj3 = 0.f;
    float bias[16], aw[16];
#pragma unroll
    for (int nb = 0; nb < 16; nb++) {
        int d = nb * 16 + m;
        bias[nb] = rel_b[r * DOUT + d];
        aw[nb] = attn_w[DOUT + d];
        sj0 += (acc[nb][0] + bias[nb]) * aw[nb];
        sj1 += (acc[nb][1] + bias[nb]) * aw[nb];
        sj2 += (acc[nb][2] + bias[nb]) * aw[nb];
        sj3 += (acc[nb][3] + bias[nb]) * aw[nb];
    }
#pragma unroll
    for (int mk = 1; mk <= 8; mk <<= 1) {
        sj0 += __shfl_xor(sj0, mk, 64);
        sj1 += __shfl_xor(sj1, mk, 64);
        sj2 += __shfl_xor(sj2, mk, 64);
        sj3 += __shfl_xor(sj3, mk, 64);
    }
    float e0 = __expf(sj0), e1 = __expf(sj1), e2 = __expf(sj2), e3 = __expf(sj3);

    int slice = b * R_ + r;
    int js = n0 >> 5;
    int jhi = (n0 >> 4) & 1;
    int qp = jhi * 2 + (q >> 1);
    int jj0 = (q & 1) * 4;
    unsigned short* fb = fswz + ((long)(slice * 32 + js) * 16) * 512
                       + qp * 128 + m * 8 + jj0;
#pragma unroll
    for (int nb = 0; nb < 16; nb++) {
        ushort4 o;
        o.x = f2bf((acc[nb][0] + bias[nb]) * e0);
        o.y = f2bf((acc[nb][1] + bias[nb]) * e1);
        o.z = f2bf((acc[nb][2] + bias[nb]) * e2);
        o.w = f2bf((acc[nb][3] + bias[nb]) * e3);
        *(ushort4*)(fb + nb * 512) = o;
    }
    if (m == 0) {
        ushort4 o;
        o.x = f2bf(e0); o.y = f2bf(e1); o.z = f2bf(e2); o.w = f2bf(e3);
        *(ushort4*)(ebf + slice * N_ + n0 + q * 4) = o;
    }
}

// ---- k2: bit-pack adj (134MB int32 -> 4.2MB bits), per-thread streaming -----
// One thread = one uint32 word: 32 ints via 8 INDEPENDENT int4 loads, local
// VALU packing. No ballot, no cross-lane, no dependent load chains.
// pk word w of row covers j = w*32..w*32+31, bit = j&31 (k3-compatible).
__global__ __launch_bounds__(256) void k2_pack(const int* __restrict__ adj,
                                               unsigned int* __restrict__ pk) {
    int t = blockIdx.x * 256 + threadIdx.x;  // 0..1,048,575 output words
    const int* src = adj + (size_t)t * 32;
    i32x4 v[8];
#pragma unroll
    for (int i = 0; i < 8; i++) v[i] = *(const i32x4*)(src + i * 4);
    unsigned int bits = 0;
#pragma unroll
    for (int i = 0; i < 8; i++) {
        bits |= (v[i].x ? 1u : 0u) << (4 * i);
        bits |= (v[i].y ? 2u : 0u) << (4 * i);
        bits |= (v[i].z ? 4u : 0u) << (4 * i);
        bits |= (v[i].w ? 8u : 0u) << (4 * i);
    }
    pk[t] = bits;
}

// ---- k3: accU = A @ G over a j-half + partial l ----------------------------
// adj as REGISTER-HELD bitmask (16 VGPRs/lane, loaded once) -> zero in-loop
// global loads except G staging (16KB/step LDS dbuf, global_load_lds).
// grid 1024 = slice(32, XCD-affine) x it(16) x jh(2); 33.8KB LDS -> 4 blk/CU.
__global__ __launch_bounds__(256, 4) void k3_attn(const unsigned int* __restrict__ pk,
        const unsigned short* __restrict__ fswz, const unsigned short* __restrict__ ebf,
        unsigned short* __restrict__ aggU, float* __restrict__ lbuf) {
    __shared__ unsigned short Gbuf[2][8192];  // 2 x 16KB
    __shared__ unsigned short Ebuf[512];      // 1KB: this j-half's e

    int bid = blockIdx.x;
    int slice = (bid & 7) * 4 + ((bid >> 3) & 3);  // XCD-affine slice grouping
    int rest = bid >> 5;
    int it = rest & 15, jh = rest >> 4;
    int t = threadIdx.x, lane = t & 63, w = t >> 6;
    int m = lane & 15, q = lane >> 4;
    int i0b = it * 64;

    const unsigned short* fsl = fswz + ((size_t)(slice * 32 + jh * 16)) * 8192;
    const unsigned short* esl = ebf + slice * N_ + jh * 512;

    // row bits for this lane's MFMA A-row: 512 bits = 16 uint32
    const unsigned int* pb = pk + ((size_t)slice * N_ + i0b + w * 16 + m) * 32 + jh * 16;
    unsigned int Wv[16];
    *(i32x4*)(&Wv[0])  = *(const i32x4*)(pb);
    *(i32x4*)(&Wv[4])  = *(const i32x4*)(pb + 4);
    *(i32x4*)(&Wv[8])  = *(const i32x4*)(pb + 8);
    *(i32x4*)(&Wv[12]) = *(const i32x4*)(pb + 12);
    int q8 = q * 8;

    // prologue: stage G step 0 + e-table
#pragma unroll
    for (int i = 0; i < 4; i++)
        gl_lds16(fsl + (w * 4 + i) * 512 + lane * 8, &Gbuf[0][(w * 4 + i) * 512]);
    if (w == 0)
        gl_lds16(esl + lane * 8, &Ebuf[0]);

    f32x4 acc[16];
#pragma unroll
    for (int i = 0; i < 16; i++) acc[i] = (f32x4)0.0f;
    float l = 0.f;

#pragma unroll
    for (int s = 0; s < 16; s++) {
        int cur = s & 1;
        __syncthreads();  // drains staging for step s
        if (s < 15) {
#pragma unroll
            for (int i = 0; i < 4; i++)
                gl_lds16(fsl + (size_t)(s + 1) * 8192 + (w * 4 + i) * 512 + lane * 8,
                         &Gbuf[cur ^ 1][(w * 4 + i) * 512]);
        }
        unsigned int byte = (Wv[s] >> q8) & 0xffu;  // 8 j-bits for this lane
        bf16x8 ev = *(const bf16x8*)(&Ebuf[s * 32 + q * 8]);
        const int* ei = (const int*)&ev;
        bf16x8 af;
        int* afi = (int*)&af;
#pragma unroll
        for (int p = 0; p < 4; p++) {
            unsigned int msk = (((byte >> (2 * p)) & 1u) ? 0xffffu : 0u)
                             | (((byte >> (2 * p + 1)) & 1u) ? 0xffff0000u : 0u);
            afi[p] = (int)(msk & 0x3F803F80u);  // A entries: bf16 1.0 / 0.0
            int me = ei[p] & (int)msk;          // masked e (bf16 pair) for l
            union { int i; float f; } lo, hi;
            lo.i = me << 16;
            hi.i = me & (int)0xffff0000u;
            l += lo.f + hi.f;
        }
        const unsigned short* Gb = &Gbuf[cur][lane * 8];
#pragma unroll
        for (int nb = 0; nb < 16; nb++) {
            bf16x8 bfq = *(const bf16x8*)(Gb + nb * 512);
            acc[nb] = __builtin_amdgcn_mfma_f32_16x16x32_bf16(af, bfq, acc[nb], 0, 0, 0);
        }
    }

    // partial l per row m: reduce over q
    l += __shfl_xor(l, 16, 64);
    l += __shfl_xor(l, 32, 64);
    int half = slice * 2 + jh;
    if (lane < 16)
        lbuf[half * N_ + i0b + w * 16 + lane] = l;

    // unnormalized accU (bf16): row = i0b + w*16 + q*4 + reg, col = nb*16 + m
    unsigned short* ob = aggU + ((size_t)half * N_ + i0b + w * 16 + q * 4) * DOUT + m;
#pragma unroll
    for (int nb = 0; nb < 16; nb++) {
#pragma unroll
        for (int reg = 0; reg < 4; reg++)
            ob[(size_t)reg * DOUT + nb * 16] = f2bf(acc[nb][reg]);
    }
}

// ---- k4: combine halves, gate, write out ------------------------------------
__global__ __launch_bounds__(256) void k4_out(const unsigned short* __restrict__ aggU,
        const float* __restrict__ lbuf, const float* __restrict__ gate_w,
        const float* __restrict__ gate_b, float* __restrict__ out) {
    __shared__ float red[4];
    int bid = blockIdx.x;  // 8192 = b*1024 + n
    int n = bid & 1023, b = bid >> 10;
    int d = threadIdx.x;
    float s = 0.f;
#pragma unroll
    for (int r = 0; r < R_; r++) {
        int sl = b * R_ + r;
        float a0 = bf2f(aggU[((size_t)(sl * 2 + 0) * N_ + n) * DOUT + d]);
        float a1 = bf2f(aggU[((size_t)(sl * 2 + 1) * N_ + n) * DOUT + d]);
        float lt = lbuf[(sl * 2 + 0) * N_ + n] + lbuf[(sl * 2 + 1) * N_ + n];
        float inv = (lt > 0.f) ? 1.0f / lt : 0.f;
        s += (a0 + a1) * inv;
    }
    float v = s * gate_w[d];
#pragma unroll
    for (int off = 32; off; off >>= 1) v += __shfl_down(v, off, 64);
    int lane = d & 63, wave = d >> 6;
    if (lane == 0) red[wave] = v;
    __syncthreads();
    float tot = red[0] + red[1] + red[2] + red[3];
    float g = 1.f / (1.f + __expf(-(tot + gate_b[0])));
    out[((long)(b * N_ + n)) * DOUT + d] = g * s;
}

extern "C" void kernel_launch(void* const* d_in, const int* in_sizes, int n_in,
                              void* d_out, int out_size, void* d_ws, size_t ws_size,
                              hipStream_t stream) {
    const float* node   = (const float*)d_in[0];
    const int*   adj    = (const int*)d_in[1];
    const float* rel_w  = (const float*)d_in[2];
    const float* rel_b  = (const float*)d_in[3];
    const float* attn_w = (const float*)d_in[4];
    // d_in[5] = attn_b: cancels in softmax, unused
    const float* gate_w = (const float*)d_in[6];
    const float* gate_b = (const float*)d_in[7];
    float* out = (float*)d_out;

    char* ws = (char*)d_ws;
    unsigned short* swzW = (unsigned short*)ws;                        // 524,288 B
    unsigned short* fswz = (unsigned short*)(ws + 524288);             // 16,777,216 B (G)
    unsigned short* ebf  = (unsigned short*)(ws + 17301504);           // 65,536 B
    unsigned short* aggU = (unsigned short*)(ws + 17367040);           // 33,554,432 B (bf16)
    float*          lbuf = (float*)(ws + 50921472);                    // 262,144 B
    unsigned int*   pk   = (unsigned int*)(ws + 51183616);             // 4,194,304 B

    k0_swz<<<128, 256, 0, stream>>>(rel_w, swzW);
    k2_pack<<<4096, 256, 0, stream>>>(adj, pk);
    k1_proj<<<512, 256, 0, stream>>>(node, swzW, rel_b, attn_w, fswz, ebf);
    k3_attn<<<1024, 256, 0, stream>>>(pk, fswz, ebf, aggU, lbuf);
    k4_out<<<8192, 256, 0, stream>>>(aggU, lbuf, gate_w, gate_b, out);
}

// Round 9
// 256.792 us; speedup vs baseline: 1.2483x; 1.0785x over previous
//
#include <hip/hip_runtime.h>
#include <hip/hip_bf16.h>

#define B_ 8
#define N_ 1024
#define DIN 256
#define DOUT 256
#define R_ 4

typedef __attribute__((ext_vector_type(8))) short bf16x8;
typedef __attribute__((ext_vector_type(4))) float f32x4;
typedef __attribute__((ext_vector_type(4))) int i32x4;

__device__ __forceinline__ unsigned short f2bf(float f) {
    union { float f; unsigned int u; } v; v.f = f;
    unsigned int u = v.u;
    u += 0x7fffu + ((u >> 16) & 1u);
    return (unsigned short)(u >> 16);
}
__device__ __forceinline__ float bf2f(unsigned short h) {
    union { float f; unsigned int u; } v; v.u = ((unsigned int)h) << 16;
    return v.f;
}

// async global->LDS, 16B/lane. LDS dest = wave-uniform base + lane*16.
__device__ __forceinline__ void gl_lds16(const void* g, void* l) {
    __builtin_amdgcn_global_load_lds(
        (const __attribute__((address_space(1))) unsigned int*)g,
        (__attribute__((address_space(3))) unsigned int*)l, 16, 0, 0);
}

// ---- k0: swizzle rel_w (f32 [R][D][K]) into bf16 MFMA B-fragment layout ----
__global__ __launch_bounds__(256) void k0_swz(const float* __restrict__ rw,
                                              unsigned short* __restrict__ swzW) {
    int t = blockIdx.x * 256 + threadIdx.x;  // 0..32767
    int lane = t & 63, nb = (t >> 6) & 15, ks = (t >> 10) & 7, r = t >> 13;
    int m = lane & 15, q = lane >> 4;
    const float* src = rw + ((r * DOUT + nb * 16 + m) * DIN) + ks * 32 + q * 8;
    float4 v0 = *(const float4*)src;
    float4 v1 = *(const float4*)(src + 4);
    bf16x8 o;
    o[0] = (short)f2bf(v0.x); o[1] = (short)f2bf(v0.y);
    o[2] = (short)f2bf(v0.z); o[3] = (short)f2bf(v0.w);
    o[4] = (short)f2bf(v1.x); o[5] = (short)f2bf(v1.y);
    o[6] = (short)f2bf(v1.z); o[7] = (short)f2bf(v1.w);
    *(bf16x8*)(swzW + (long)t * 8) = o;
}

// ---- k1: G[j][d] = e[j]*(node@rel_w^T + rel_b)[j][d], B-fragment layout -----
__global__ __launch_bounds__(256) void k1_proj(const float* __restrict__ node,
        const unsigned short* __restrict__ swzW, const float* __restrict__ rel_b,
        const float* __restrict__ attn_w,
        unsigned short* __restrict__ fswz, unsigned short* __restrict__ ebf) {
    __shared__ unsigned short Wbuf[2][8192];
    int bid = blockIdx.x;
    int nt = bid & 15, r = (bid >> 4) & 3, b = bid >> 6;
    int w = threadIdx.x >> 6, lane = threadIdx.x & 63;
    int m = lane & 15, q = lane >> 4;
    int n0 = nt * 64 + w * 16;

    const float* Abase = node + ((b * N_ + n0 + m) * DIN) + q * 8;
    const unsigned short* Wsrc = swzW + r * 65536;

#pragma unroll
    for (int i = 0; i < 4; i++)
        gl_lds16(Wsrc + (w * 4 + i) * 512 + lane * 8, &Wbuf[0][(w * 4 + i) * 512]);

    f32x4 acc[16];
#pragma unroll
    for (int i = 0; i < 16; i++) acc[i] = (f32x4)0.0f;

    float4 a0 = *(const float4*)(Abase);
    float4 a1 = *(const float4*)(Abase + 4);

    for (int ks = 0; ks < 8; ks++) {
        int cur = ks & 1;
        __syncthreads();
        if (ks < 7) {
#pragma unroll
            for (int i = 0; i < 4; i++)
                gl_lds16(Wsrc + ((ks + 1) * 16 + w * 4 + i) * 512 + lane * 8,
                         &Wbuf[cur ^ 1][(w * 4 + i) * 512]);
        }
        bf16x8 af;
        af[0] = (short)f2bf(a0.x); af[1] = (short)f2bf(a0.y);
        af[2] = (short)f2bf(a0.z); af[3] = (short)f2bf(a0.w);
        af[4] = (short)f2bf(a1.x); af[5] = (short)f2bf(a1.y);
        af[6] = (short)f2bf(a1.z); af[7] = (short)f2bf(a1.w);
        if (ks < 7) {
            a0 = *(const float4*)(Abase + (ks + 1) * 32);
            a1 = *(const float4*)(Abase + (ks + 1) * 32 + 4);
        }
#pragma unroll
        for (int nb = 0; nb < 16; nb++) {
            bf16x8 wf = *(const bf16x8*)(&Wbuf[cur][nb * 512 + lane * 8]);
            acc[nb] = __builtin_amdgcn_mfma_f32_16x16x32_bf16(af, wf, acc[nb], 0, 0, 0);
        }
    }

    float sj0 = 0.f, sj1 = 0.f, sj2 = 0.f, sj3 = 0.f;
    float bias[16], aw[16];
#pragma unroll
    for (int nb = 0; nb < 16; nb++) {
        int d = nb * 16 + m;
        bias[nb] = rel_b[r * DOUT + d];
        aw[nb] = attn_w[DOUT + d];
        sj0 += (acc[nb][0] + bias[nb]) * aw[nb];
        sj1 += (acc[nb][1] + bias[nb]) * aw[nb];
        sj2 += (acc[nb][2] + bias[nb]) * aw[nb];
        sj3 += (acc[nb][3] + bias[nb]) * aw[nb];
    }
#pragma unroll
    for (int mk = 1; mk <= 8; mk <<= 1) {
        sj0 += __shfl_xor(sj0, mk, 64);
        sj1 += __shfl_xor(sj1, mk, 64);
        sj2 += __shfl_xor(sj2, mk, 64);
        sj3 += __shfl_xor(sj3, mk, 64);
    }
    float e0 = __expf(sj0), e1 = __expf(sj1), e2 = __expf(sj2), e3 = __expf(sj3);

    int slice = b * R_ + r;
    int js = n0 >> 5;
    int jhi = (n0 >> 4) & 1;
    int qp = jhi * 2 + (q >> 1);
    int jj0 = (q & 1) * 4;
    unsigned short* fb = fswz + ((long)(slice * 32 + js) * 16) * 512
                       + qp * 128 + m * 8 + jj0;
#pragma unroll
    for (int nb = 0; nb < 16; nb++) {
        ushort4 o;
        o.x = f2bf((acc[nb][0] + bias[nb]) * e0);
        o.y = f2bf((acc[nb][1] + bias[nb]) * e1);
        o.z = f2bf((acc[nb][2] + bias[nb]) * e2);
        o.w = f2bf((acc[nb][3] + bias[nb]) * e3);
        *(ushort4*)(fb + nb * 512) = o;
    }
    if (m == 0) {
        ushort4 o;
        o.x = f2bf(e0); o.y = f2bf(e1); o.z = f2bf(e2); o.w = f2bf(e3);
        *(ushort4*)(ebf + slice * N_ + n0 + q * 4) = o;
    }
}

// ---- k2: bit-pack adj (134MB int32 -> 4.2MB bits), per-thread streaming -----
__global__ __launch_bounds__(256) void k2_pack(const int* __restrict__ adj,
                                               unsigned int* __restrict__ pk) {
    int t = blockIdx.x * 256 + threadIdx.x;  // 0..1,048,575 output words
    const int* src = adj + (size_t)t * 32;
    i32x4 v[8];
#pragma unroll
    for (int i = 0; i < 8; i++) v[i] = *(const i32x4*)(src + i * 4);
    unsigned int bits = 0;
#pragma unroll
    for (int i = 0; i < 8; i++) {
        bits |= (v[i].x ? 1u : 0u) << (4 * i);
        bits |= (v[i].y ? 2u : 0u) << (4 * i);
        bits |= (v[i].z ? 4u : 0u) << (4 * i);
        bits |= (v[i].w ? 8u : 0u) << (4 * i);
    }
    pk[t] = bits;
}

// ---- k3: accU = A @ G over a j-half + partial l, A-PAIR blocked ------------
// Each wave carries TWO A-fragments (rows i0.. and i0+64..) -> each B-frag
// ds_read feeds 2 MFMAs. Block = 128 rows; half the block-step walls and
// half the LDS-read bytes per MFMA of the unpaired version.
// grid 512 = slice(32, XCD-affine) x pair(8) x jh(2); 2 blocks/CU.
__global__ __launch_bounds__(256, 2) void k3_attn(const unsigned int* __restrict__ pk,
        const unsigned short* __restrict__ fswz, const unsigned short* __restrict__ ebf,
        unsigned short* __restrict__ aggU, float* __restrict__ lbuf) {
    __shared__ unsigned short Gbuf[2][8192];  // 2 x 16KB
    __shared__ unsigned short Ebuf[512];      // 1KB: this j-half's e

    int bid = blockIdx.x;
    int slice = (bid & 7) * 4 + ((bid >> 3) & 3);  // XCD-affine slice grouping
    int rest = bid >> 5;
    int pair = rest & 7, jh = rest >> 3;
    int t = threadIdx.x, lane = t & 63, w = t >> 6;
    int m = lane & 15, q = lane >> 4;
    int i0b = pair * 128;

    const unsigned short* fsl = fswz + ((size_t)(slice * 32 + jh * 16)) * 8192;
    const unsigned short* esl = ebf + slice * N_ + jh * 512;

    // j-half bits for the two A-rows this lane covers: 16 uint32 each
    const unsigned int* pA = pk + ((size_t)slice * N_ + i0b + w * 16 + m) * 32 + jh * 16;
    const unsigned int* pB = pA + 64 * 32;  // row + 64
    unsigned int Wa[16], Wb[16];
#pragma unroll
    for (int i = 0; i < 4; i++) *(i32x4*)(&Wa[i * 4]) = *(const i32x4*)(pA + i * 4);
#pragma unroll
    for (int i = 0; i < 4; i++) *(i32x4*)(&Wb[i * 4]) = *(const i32x4*)(pB + i * 4);
    int q8 = q * 8;

    // prologue: stage G step 0 + e-table
#pragma unroll
    for (int i = 0; i < 4; i++)
        gl_lds16(fsl + (w * 4 + i) * 512 + lane * 8, &Gbuf[0][(w * 4 + i) * 512]);
    if (w == 0)
        gl_lds16(esl + lane * 8, &Ebuf[0]);

    f32x4 accA[16], accB[16];
#pragma unroll
    for (int i = 0; i < 16; i++) { accA[i] = (f32x4)0.0f; accB[i] = (f32x4)0.0f; }
    float lA = 0.f, lB = 0.f;

#pragma unroll
    for (int s = 0; s < 16; s++) {
        int cur = s & 1;
        __syncthreads();  // drains staging for step s
        if (s < 15) {
#pragma unroll
            for (int i = 0; i < 4; i++)
                gl_lds16(fsl + (size_t)(s + 1) * 8192 + (w * 4 + i) * 512 + lane * 8,
                         &Gbuf[cur ^ 1][(w * 4 + i) * 512]);
        }
        unsigned int byteA = (Wa[s] >> q8) & 0xffu;
        unsigned int byteB = (Wb[s] >> q8) & 0xffu;
        bf16x8 ev = *(const bf16x8*)(&Ebuf[s * 32 + q * 8]);
        const int* ei = (const int*)&ev;
        bf16x8 afA, afB;
        int* aiA = (int*)&afA;
        int* aiB = (int*)&afB;
#pragma unroll
        for (int p = 0; p < 4; p++) {
            unsigned int mA = (((byteA >> (2 * p)) & 1u) ? 0xffffu : 0u)
                            | (((byteA >> (2 * p + 1)) & 1u) ? 0xffff0000u : 0u);
            unsigned int mB = (((byteB >> (2 * p)) & 1u) ? 0xffffu : 0u)
                            | (((byteB >> (2 * p + 1)) & 1u) ? 0xffff0000u : 0u);
            aiA[p] = (int)(mA & 0x3F803F80u);
            aiB[p] = (int)(mB & 0x3F803F80u);
            int meA = ei[p] & (int)mA;
            int meB = ei[p] & (int)mB;
            union { int i; float f; } lo, hi;
            lo.i = meA << 16; hi.i = meA & (int)0xffff0000u;
            lA += lo.f + hi.f;
            lo.i = meB << 16; hi.i = meB & (int)0xffff0000u;
            lB += lo.f + hi.f;
        }
        const unsigned short* Gb = &Gbuf[cur][lane * 8];
#pragma unroll
        for (int nb = 0; nb < 16; nb++) {
            bf16x8 bfq = *(const bf16x8*)(Gb + nb * 512);
            accA[nb] = __builtin_amdgcn_mfma_f32_16x16x32_bf16(afA, bfq, accA[nb], 0, 0, 0);
            accB[nb] = __builtin_amdgcn_mfma_f32_16x16x32_bf16(afB, bfq, accB[nb], 0, 0, 0);
        }
    }

    // partial l per row m: reduce over q
    lA += __shfl_xor(lA, 16, 64);
    lA += __shfl_xor(lA, 32, 64);
    lB += __shfl_xor(lB, 16, 64);
    lB += __shfl_xor(lB, 32, 64);
    int half = slice * 2 + jh;
    if (lane < 16) {
        lbuf[half * N_ + i0b + w * 16 + lane] = lA;
        lbuf[half * N_ + i0b + 64 + w * 16 + lane] = lB;
    }

    // unnormalized accU (bf16): rows i0b+w*16+q*4+reg (A) and +64 (B)
    unsigned short* obA = aggU + ((size_t)half * N_ + i0b + w * 16 + q * 4) * DOUT + m;
    unsigned short* obB = obA + (size_t)64 * DOUT;
#pragma unroll
    for (int nb = 0; nb < 16; nb++) {
#pragma unroll
        for (int reg = 0; reg < 4; reg++) {
            obA[(size_t)reg * DOUT + nb * 16] = f2bf(accA[nb][reg]);
            obB[(size_t)reg * DOUT + nb * 16] = f2bf(accB[nb][reg]);
        }
    }
}

// ---- k4: combine halves, gate, write out ------------------------------------
__global__ __launch_bounds__(256) void k4_out(const unsigned short* __restrict__ aggU,
        const float* __restrict__ lbuf, const float* __restrict__ gate_w,
        const float* __restrict__ gate_b, float* __restrict__ out) {
    __shared__ float red[4];
    int bid = blockIdx.x;  // 8192 = b*1024 + n
    int n = bid & 1023, b = bid >> 10;
    int d = threadIdx.x;
    float s = 0.f;
#pragma unroll
    for (int r = 0; r < R_; r++) {
        int sl = b * R_ + r;
        float a0 = bf2f(aggU[((size_t)(sl * 2 + 0) * N_ + n) * DOUT + d]);
        float a1 = bf2f(aggU[((size_t)(sl * 2 + 1) * N_ + n) * DOUT + d]);
        float lt = lbuf[(sl * 2 + 0) * N_ + n] + lbuf[(sl * 2 + 1) * N_ + n];
        float inv = (lt > 0.f) ? 1.0f / lt : 0.f;
        s += (a0 + a1) * inv;
    }
    float v = s * gate_w[d];
#pragma unroll
    for (int off = 32; off; off >>= 1) v += __shfl_down(v, off, 64);
    int lane = d & 63, wave = d >> 6;
    if (lane == 0) red[wave] = v;
    __syncthreads();
    float tot = red[0] + red[1] + red[2] + red[3];
    float g = 1.f / (1.f + __expf(-(tot + gate_b[0])));
    out[((long)(b * N_ + n)) * DOUT + d] = g * s;
}

extern "C" void kernel_launch(void* const* d_in, const int* in_sizes, int n_in,
                              void* d_out, int out_size, void* d_ws, size_t ws_size,
                              hipStream_t stream) {
    const float* node   = (const float*)d_in[0];
    const int*   adj    = (const int*)d_in[1];
    const float* rel_w  = (const float*)d_in[2];
    const float* rel_b  = (const float*)d_in[3];
    const float* attn_w = (const float*)d_in[4];
    // d_in[5] = attn_b: cancels in softmax, unused
    const float* gate_w = (const float*)d_in[6];
    const float* gate_b = (const float*)d_in[7];
    float* out = (float*)d_out;

    char* ws = (char*)d_ws;
    unsigned short* swzW = (unsigned short*)ws;                        // 524,288 B
    unsigned short* fswz = (unsigned short*)(ws + 524288);             // 16,777,216 B (G)
    unsigned short* ebf  = (unsigned short*)(ws + 17301504);           // 65,536 B
    unsigned short* aggU = (unsigned short*)(ws + 17367040);           // 33,554,432 B (bf16)
    float*          lbuf = (float*)(ws + 50921472);                    // 262,144 B
    unsigned int*   pk   = (unsigned int*)(ws + 51183616);             // 4,194,304 B

    k0_swz<<<128, 256, 0, stream>>>(rel_w, swzW);
    k2_pack<<<4096, 256, 0, stream>>>(adj, pk);
    k1_proj<<<512, 256, 0, stream>>>(node, swzW, rel_b, attn_w, fswz, ebf);
    k3_attn<<<512, 256, 0, stream>>>(pk, fswz, ebf, aggU, lbuf);
    k4_out<<<8192, 256, 0, stream>>>(aggU, lbuf, gate_w, gate_b, out);
}

// Round 10
// 256.319 us; speedup vs baseline: 1.2506x; 1.0018x over previous
//
#include <hip/hip_runtime.h>
#include <hip/hip_bf16.h>

#define B_ 8
#define N_ 1024
#define DIN 256
#define DOUT 256
#define R_ 4

typedef __attribute__((ext_vector_type(8))) short bf16x8;
typedef __attribute__((ext_vector_type(4))) float f32x4;
typedef __attribute__((ext_vector_type(4))) int i32x4;

__device__ __forceinline__ unsigned short f2bf(float f) {
    union { float f; unsigned int u; } v; v.f = f;
    unsigned int u = v.u;
    u += 0x7fffu + ((u >> 16) & 1u);
    return (unsigned short)(u >> 16);
}
__device__ __forceinline__ float bf2f(unsigned short h) {
    union { float f; unsigned int u; } v; v.u = ((unsigned int)h) << 16;
    return v.f;
}

// async global->LDS, 16B/lane. LDS dest = wave-uniform base + lane*16.
__device__ __forceinline__ void gl_lds16(const void* g, void* l) {
    __builtin_amdgcn_global_load_lds(
        (const __attribute__((address_space(1))) unsigned int*)g,
        (__attribute__((address_space(3))) unsigned int*)l, 16, 0, 0);
}

// ---- k0: swizzle rel_w (f32 [R][D][K]) into bf16 MFMA B-fragment layout ----
__global__ __launch_bounds__(256) void k0_swz(const float* __restrict__ rw,
                                              unsigned short* __restrict__ swzW) {
    int t = blockIdx.x * 256 + threadIdx.x;  // 0..32767
    int lane = t & 63, nb = (t >> 6) & 15, ks = (t >> 10) & 7, r = t >> 13;
    int m = lane & 15, q = lane >> 4;
    const float* src = rw + ((r * DOUT + nb * 16 + m) * DIN) + ks * 32 + q * 8;
    float4 v0 = *(const float4*)src;
    float4 v1 = *(const float4*)(src + 4);
    bf16x8 o;
    o[0] = (short)f2bf(v0.x); o[1] = (short)f2bf(v0.y);
    o[2] = (short)f2bf(v0.z); o[3] = (short)f2bf(v0.w);
    o[4] = (short)f2bf(v1.x); o[5] = (short)f2bf(v1.y);
    o[6] = (short)f2bf(v1.z); o[7] = (short)f2bf(v1.w);
    *(bf16x8*)(swzW + (long)t * 8) = o;
}

// ---- k1: G[j][d] = e[j]*(node@rel_w^T + rel_b)[j][d], A-PAIR blocked --------
// 128-thread blocks (2 waves); each wave holds TWO A-frags (rows n0, n0+16)
// -> each staged W-frag feeds 2 MFMAs. grid 512 = (b,r,nt); ~4 blocks/CU.
__global__ __launch_bounds__(128, 2) void k1_proj(const float* __restrict__ node,
        const unsigned short* __restrict__ swzW, const float* __restrict__ rel_b,
        const float* __restrict__ attn_w,
        unsigned short* __restrict__ fswz, unsigned short* __restrict__ ebf) {
    __shared__ unsigned short Wbuf[2][8192];
    int bid = blockIdx.x;
    int nt = bid & 15, r = (bid >> 4) & 3, b = bid >> 6;
    int w = threadIdx.x >> 6, lane = threadIdx.x & 63;  // w in {0,1}
    int m = lane & 15, q = lane >> 4;
    int n0 = nt * 64 + w * 32;

    const float* AbaseA = node + ((b * N_ + n0 + m) * DIN) + q * 8;
    const float* AbaseB = AbaseA + 16 * DIN;
    const unsigned short* Wsrc = swzW + r * 65536;

#pragma unroll
    for (int i = 0; i < 8; i++)
        gl_lds16(Wsrc + (w * 8 + i) * 512 + lane * 8, &Wbuf[0][(w * 8 + i) * 512]);

    f32x4 accA[16], accB[16];
#pragma unroll
    for (int i = 0; i < 16; i++) { accA[i] = (f32x4)0.0f; accB[i] = (f32x4)0.0f; }

    float4 a0A = *(const float4*)(AbaseA);
    float4 a1A = *(const float4*)(AbaseA + 4);
    float4 a0B = *(const float4*)(AbaseB);
    float4 a1B = *(const float4*)(AbaseB + 4);

    for (int ks = 0; ks < 8; ks++) {
        int cur = ks & 1;
        __syncthreads();
        if (ks < 7) {
#pragma unroll
            for (int i = 0; i < 8; i++)
                gl_lds16(Wsrc + ((ks + 1) * 16 + w * 8 + i) * 512 + lane * 8,
                         &Wbuf[cur ^ 1][(w * 8 + i) * 512]);
        }
        bf16x8 afA, afB;
        afA[0] = (short)f2bf(a0A.x); afA[1] = (short)f2bf(a0A.y);
        afA[2] = (short)f2bf(a0A.z); afA[3] = (short)f2bf(a0A.w);
        afA[4] = (short)f2bf(a1A.x); afA[5] = (short)f2bf(a1A.y);
        afA[6] = (short)f2bf(a1A.z); afA[7] = (short)f2bf(a1A.w);
        afB[0] = (short)f2bf(a0B.x); afB[1] = (short)f2bf(a0B.y);
        afB[2] = (short)f2bf(a0B.z); afB[3] = (short)f2bf(a0B.w);
        afB[4] = (short)f2bf(a1B.x); afB[5] = (short)f2bf(a1B.y);
        afB[6] = (short)f2bf(a1B.z); afB[7] = (short)f2bf(a1B.w);
        if (ks < 7) {
            a0A = *(const float4*)(AbaseA + (ks + 1) * 32);
            a1A = *(const float4*)(AbaseA + (ks + 1) * 32 + 4);
            a0B = *(const float4*)(AbaseB + (ks + 1) * 32);
            a1B = *(const float4*)(AbaseB + (ks + 1) * 32 + 4);
        }
#pragma unroll
        for (int nb = 0; nb < 16; nb++) {
            bf16x8 wf = *(const bf16x8*)(&Wbuf[cur][nb * 512 + lane * 8]);
            accA[nb] = __builtin_amdgcn_mfma_f32_16x16x32_bf16(afA, wf, accA[nb], 0, 0, 0);
            accB[nb] = __builtin_amdgcn_mfma_f32_16x16x32_bf16(afB, wf, accB[nb], 0, 0, 0);
        }
    }

    // C layout per frag: row n = base + q*4 + reg, col d = nb*16 + m.
    float sA0 = 0.f, sA1 = 0.f, sA2 = 0.f, sA3 = 0.f;
    float sB0 = 0.f, sB1 = 0.f, sB2 = 0.f, sB3 = 0.f;
    float bias[16], aw[16];
#pragma unroll
    for (int nb = 0; nb < 16; nb++) {
        int d = nb * 16 + m;
        bias[nb] = rel_b[r * DOUT + d];
        aw[nb] = attn_w[DOUT + d];
        sA0 += (accA[nb][0] + bias[nb]) * aw[nb];
        sA1 += (accA[nb][1] + bias[nb]) * aw[nb];
        sA2 += (accA[nb][2] + bias[nb]) * aw[nb];
        sA3 += (accA[nb][3] + bias[nb]) * aw[nb];
        sB0 += (accB[nb][0] + bias[nb]) * aw[nb];
        sB1 += (accB[nb][1] + bias[nb]) * aw[nb];
        sB2 += (accB[nb][2] + bias[nb]) * aw[nb];
        sB3 += (accB[nb][3] + bias[nb]) * aw[nb];
    }
#pragma unroll
    for (int mk = 1; mk <= 8; mk <<= 1) {
        sA0 += __shfl_xor(sA0, mk, 64); sA1 += __shfl_xor(sA1, mk, 64);
        sA2 += __shfl_xor(sA2, mk, 64); sA3 += __shfl_xor(sA3, mk, 64);
        sB0 += __shfl_xor(sB0, mk, 64); sB1 += __shfl_xor(sB1, mk, 64);
        sB2 += __shfl_xor(sB2, mk, 64); sB3 += __shfl_xor(sB3, mk, 64);
    }
    float eA0 = __expf(sA0), eA1 = __expf(sA1), eA2 = __expf(sA2), eA3 = __expf(sA3);
    float eB0 = __expf(sB0), eB1 = __expf(sB1), eB2 = __expf(sB2), eB3 = __expf(sB3);

    int slice = b * R_ + r;
    int js = n0 >> 5;                 // n0 multiple of 32: frag A jhi=0, frag B jhi=1
    int jj0 = (q & 1) * 4;
    unsigned short* base = fswz + ((long)(slice * 32 + js) * 16) * 512 + m * 8 + jj0;
    unsigned short* fbA = base + (0 * 2 + (q >> 1)) * 128;
    unsigned short* fbB = base + (1 * 2 + (q >> 1)) * 128;
#pragma unroll
    for (int nb = 0; nb < 16; nb++) {
        ushort4 oA, oB;
        oA.x = f2bf((accA[nb][0] + bias[nb]) * eA0);
        oA.y = f2bf((accA[nb][1] + bias[nb]) * eA1);
        oA.z = f2bf((accA[nb][2] + bias[nb]) * eA2);
        oA.w = f2bf((accA[nb][3] + bias[nb]) * eA3);
        oB.x = f2bf((accB[nb][0] + bias[nb]) * eB0);
        oB.y = f2bf((accB[nb][1] + bias[nb]) * eB1);
        oB.z = f2bf((accB[nb][2] + bias[nb]) * eB2);
        oB.w = f2bf((accB[nb][3] + bias[nb]) * eB3);
        *(ushort4*)(fbA + nb * 512) = oA;
        *(ushort4*)(fbB + nb * 512) = oB;
    }
    if (m == 0) {
        ushort4 oA, oB;
        oA.x = f2bf(eA0); oA.y = f2bf(eA1); oA.z = f2bf(eA2); oA.w = f2bf(eA3);
        oB.x = f2bf(eB0); oB.y = f2bf(eB1); oB.z = f2bf(eB2); oB.w = f2bf(eB3);
        *(ushort4*)(ebf + slice * N_ + n0 + q * 4) = oA;
        *(ushort4*)(ebf + slice * N_ + n0 + 16 + q * 4) = oB;
    }
}

// ---- k2: bit-pack adj (134MB int32 -> 4.2MB bits), per-thread streaming -----
__global__ __launch_bounds__(256) void k2_pack(const int* __restrict__ adj,
                                               unsigned int* __restrict__ pk) {
    int t = blockIdx.x * 256 + threadIdx.x;  // 0..1,048,575 output words
    const int* src = adj + (size_t)t * 32;
    i32x4 v[8];
#pragma unroll
    for (int i = 0; i < 8; i++) v[i] = *(const i32x4*)(src + i * 4);
    unsigned int bits = 0;
#pragma unroll
    for (int i = 0; i < 8; i++) {
        bits |= (v[i].x ? 1u : 0u) << (4 * i);
        bits |= (v[i].y ? 2u : 0u) << (4 * i);
        bits |= (v[i].z ? 4u : 0u) << (4 * i);
        bits |= (v[i].w ? 8u : 0u) << (4 * i);
    }
    pk[t] = bits;
}

// ---- k3: accU = A @ G over a j-half + partial l, A-PAIR blocked ------------
// grid 512 = slice(32, XCD-affine) x pair(8) x jh(2); 2 blocks/CU.
__global__ __launch_bounds__(256, 2) void k3_attn(const unsigned int* __restrict__ pk,
        const unsigned short* __restrict__ fswz, const unsigned short* __restrict__ ebf,
        unsigned short* __restrict__ aggU, float* __restrict__ lbuf) {
    __shared__ unsigned short Gbuf[2][8192];  // 2 x 16KB
    __shared__ unsigned short Ebuf[512];      // 1KB: this j-half's e

    int bid = blockIdx.x;
    int slice = (bid & 7) * 4 + ((bid >> 3) & 3);  // XCD-affine slice grouping
    int rest = bid >> 5;
    int pair = rest & 7, jh = rest >> 3;
    int t = threadIdx.x, lane = t & 63, w = t >> 6;
    int m = lane & 15, q = lane >> 4;
    int i0b = pair * 128;

    const unsigned short* fsl = fswz + ((size_t)(slice * 32 + jh * 16)) * 8192;
    const unsigned short* esl = ebf + slice * N_ + jh * 512;

    const unsigned int* pA = pk + ((size_t)slice * N_ + i0b + w * 16 + m) * 32 + jh * 16;
    const unsigned int* pB = pA + 64 * 32;  // row + 64
    unsigned int Wa[16], Wb[16];
#pragma unroll
    for (int i = 0; i < 4; i++) *(i32x4*)(&Wa[i * 4]) = *(const i32x4*)(pA + i * 4);
#pragma unroll
    for (int i = 0; i < 4; i++) *(i32x4*)(&Wb[i * 4]) = *(const i32x4*)(pB + i * 4);
    int q8 = q * 8;

#pragma unroll
    for (int i = 0; i < 4; i++)
        gl_lds16(fsl + (w * 4 + i) * 512 + lane * 8, &Gbuf[0][(w * 4 + i) * 512]);
    if (w == 0)
        gl_lds16(esl + lane * 8, &Ebuf[0]);

    f32x4 accA[16], accB[16];
#pragma unroll
    for (int i = 0; i < 16; i++) { accA[i] = (f32x4)0.0f; accB[i] = (f32x4)0.0f; }
    float lA = 0.f, lB = 0.f;

#pragma unroll
    for (int s = 0; s < 16; s++) {
        int cur = s & 1;
        __syncthreads();
        if (s < 15) {
#pragma unroll
            for (int i = 0; i < 4; i++)
                gl_lds16(fsl + (size_t)(s + 1) * 8192 + (w * 4 + i) * 512 + lane * 8,
                         &Gbuf[cur ^ 1][(w * 4 + i) * 512]);
        }
        unsigned int byteA = (Wa[s] >> q8) & 0xffu;
        unsigned int byteB = (Wb[s] >> q8) & 0xffu;
        bf16x8 ev = *(const bf16x8*)(&Ebuf[s * 32 + q * 8]);
        const int* ei = (const int*)&ev;
        bf16x8 afA, afB;
        int* aiA = (int*)&afA;
        int* aiB = (int*)&afB;
#pragma unroll
        for (int p = 0; p < 4; p++) {
            unsigned int mA = (((byteA >> (2 * p)) & 1u) ? 0xffffu : 0u)
                            | (((byteA >> (2 * p + 1)) & 1u) ? 0xffff0000u : 0u);
            unsigned int mB = (((byteB >> (2 * p)) & 1u) ? 0xffffu : 0u)
                            | (((byteB >> (2 * p + 1)) & 1u) ? 0xffff0000u : 0u);
            aiA[p] = (int)(mA & 0x3F803F80u);
            aiB[p] = (int)(mB & 0x3F803F80u);
            int meA = ei[p] & (int)mA;
            int meB = ei[p] & (int)mB;
            union { int i; float f; } lo, hi;
            lo.i = meA << 16; hi.i = meA & (int)0xffff0000u;
            lA += lo.f + hi.f;
            lo.i = meB << 16; hi.i = meB & (int)0xffff0000u;
            lB += lo.f + hi.f;
        }
        const unsigned short* Gb = &Gbuf[cur][lane * 8];
#pragma unroll
        for (int nb = 0; nb < 16; nb++) {
            bf16x8 bfq = *(const bf16x8*)(Gb + nb * 512);
            accA[nb] = __builtin_amdgcn_mfma_f32_16x16x32_bf16(afA, bfq, accA[nb], 0, 0, 0);
            accB[nb] = __builtin_amdgcn_mfma_f32_16x16x32_bf16(afB, bfq, accB[nb], 0, 0, 0);
        }
    }

    lA += __shfl_xor(lA, 16, 64);
    lA += __shfl_xor(lA, 32, 64);
    lB += __shfl_xor(lB, 16, 64);
    lB += __shfl_xor(lB, 32, 64);
    int half = slice * 2 + jh;
    if (lane < 16) {
        lbuf[half * N_ + i0b + w * 16 + lane] = lA;
        lbuf[half * N_ + i0b + 64 + w * 16 + lane] = lB;
    }

    unsigned short* obA = aggU + ((size_t)half * N_ + i0b + w * 16 + q * 4) * DOUT + m;
    unsigned short* obB = obA + (size_t)64 * DOUT;
#pragma unroll
    for (int nb = 0; nb < 16; nb++) {
#pragma unroll
        for (int reg = 0; reg < 4; reg++) {
            obA[(size_t)reg * DOUT + nb * 16] = f2bf(accA[nb][reg]);
            obB[(size_t)reg * DOUT + nb * 16] = f2bf(accB[nb][reg]);
        }
    }
}

// ---- k4: combine halves, gate, write out — wave-per-n, 4 d/lane -------------
__global__ __launch_bounds__(256) void k4_out(const unsigned short* __restrict__ aggU,
        const float* __restrict__ lbuf, const float* __restrict__ gate_w,
        const float* __restrict__ gate_b, float* __restrict__ out) {
    int w = threadIdx.x >> 6, lane = threadIdx.x & 63;
    int n = blockIdx.x * 4 + w;  // grid 2048
    int nn = n & 1023, b = n >> 10;
    int d0 = lane * 4;
    float s0 = 0.f, s1 = 0.f, s2 = 0.f, s3 = 0.f;
#pragma unroll
    for (int r = 0; r < R_; r++) {
        int sl = b * R_ + r;
        ushort4 u0 = *(const ushort4*)(aggU + ((size_t)(sl * 2 + 0) * N_ + nn) * DOUT + d0);
        ushort4 u1 = *(const ushort4*)(aggU + ((size_t)(sl * 2 + 1) * N_ + nn) * DOUT + d0);
        float lt = lbuf[(sl * 2 + 0) * N_ + nn] + lbuf[(sl * 2 + 1) * N_ + nn];
        float inv = (lt > 0.f) ? 1.0f / lt : 0.f;
        s0 += (bf2f(u0.x) + bf2f(u1.x)) * inv;
        s1 += (bf2f(u0.y) + bf2f(u1.y)) * inv;
        s2 += (bf2f(u0.z) + bf2f(u1.z)) * inv;
        s3 += (bf2f(u0.w) + bf2f(u1.w)) * inv;
    }
    float4 gw = *(const float4*)(gate_w + d0);
    float v = s0 * gw.x + s1 * gw.y + s2 * gw.z + s3 * gw.w;
#pragma unroll
    for (int off = 32; off; off >>= 1) v += __shfl_down(v, off, 64);
    float tot = __shfl(v, 0, 64);
    float g = 1.f / (1.f + __expf(-(tot + gate_b[0])));
    float4 o;
    o.x = g * s0; o.y = g * s1; o.z = g * s2; o.w = g * s3;
    *(float4*)(out + ((long)(b * N_ + nn)) * DOUT + d0) = o;
}

extern "C" void kernel_launch(void* const* d_in, const int* in_sizes, int n_in,
                              void* d_out, int out_size, void* d_ws, size_t ws_size,
                              hipStream_t stream) {
    const float* node   = (const float*)d_in[0];
    const int*   adj    = (const int*)d_in[1];
    const float* rel_w  = (const float*)d_in[2];
    const float* rel_b  = (const float*)d_in[3];
    const float* attn_w = (const float*)d_in[4];
    // d_in[5] = attn_b: cancels in softmax, unused
    const float* gate_w = (const float*)d_in[6];
    const float* gate_b = (const float*)d_in[7];
    float* out = (float*)d_out;

    char* ws = (char*)d_ws;
    unsigned short* swzW = (unsigned short*)ws;                        // 524,288 B
    unsigned short* fswz = (unsigned short*)(ws + 524288);             // 16,777,216 B (G)
    unsigned short* ebf  = (unsigned short*)(ws + 17301504);           // 65,536 B
    unsigned short* aggU = (unsigned short*)(ws + 17367040);           // 33,554,432 B (bf16)
    float*          lbuf = (float*)(ws + 50921472);                    // 262,144 B
    unsigned int*   pk   = (unsigned int*)(ws + 51183616);             // 4,194,304 B

    k0_swz<<<128, 256, 0, stream>>>(rel_w, swzW);
    k2_pack<<<4096, 256, 0, stream>>>(adj, pk);
    k1_proj<<<512, 128, 0, stream>>>(node, swzW, rel_b, attn_w, fswz, ebf);
    k3_attn<<<512, 256, 0, stream>>>(pk, fswz, ebf, aggU, lbuf);
    k4_out<<<2048, 256, 0, stream>>>(aggU, lbuf, gate_w, gate_b, out);
}